// Round 1
// 1273.087 us; speedup vs baseline: 1.0759x; 1.0759x over previous
//
#include <hip/hip_runtime.h>
#include <stdint.h>

#define M_NODES 100000
#define NUM_EDGES 3200000
#define IN_DIM 512
#define HIDDEN 256
#define NCLS 64

typedef __bf16 bf16x8 __attribute__((ext_vector_type(8)));
typedef float floatx4 __attribute__((ext_vector_type(4)));
typedef unsigned int uintx4 __attribute__((ext_vector_type(4)));
typedef unsigned short ushortx8 __attribute__((ext_vector_type(8)));

// ---- workspace layout (bytes) ----
// rp   : int[100001]            @ 0
// w1t  : ushort[256*512]        @ 400016
// w2t  : ushort[64*256]         @ 662160
// h1   : ushort[100000*256]     @ 694928     (dead after gemm2; bB aliases it)
// bB   : ushort[100000*64]      @ 694928     (alias of h1)
// fA   : float[100000*64]       @ 51894928
// fB   : float[100000*64]       @ 77494928
// bA   : ushort[100000*64]      @ 103094928
#define WS_ROWPTR 0
#define WS_W1T    400016
#define WS_W2T    662160
#define WS_H1     694928
#define WS_BB     694928
#define WS_FA     51894928
#define WS_FB     77494928
#define WS_BA     103094928

// ---------------- weight transpose + bf16 convert ----------------
__global__ __launch_bounds__(256) void prep_weights(
    const float* __restrict__ W1, const float* __restrict__ W2,
    unsigned short* __restrict__ w1t, unsigned short* __restrict__ w2t) {
  int tid = blockIdx.x * 256 + threadIdx.x;
  if (tid < IN_DIM * HIDDEN) {
    int n = tid >> 9;
    int k = tid & 511;
    __bf16 v = (__bf16)W1[k * HIDDEN + n];
    w1t[tid] = __builtin_bit_cast(unsigned short, v);
  } else {
    int idx = tid - IN_DIM * HIDDEN;
    if (idx < HIDDEN * NCLS) {
      int n = idx >> 8;
      int k = idx & 255;
      __bf16 v = (__bf16)W2[k * NCLS + n];
      w2t[idx] = __builtin_bit_cast(unsigned short, v);
    }
  }
}

// ---------------- row_ptr via binary search over sorted edge_row ----------------
__global__ __launch_bounds__(256) void build_rowptr(
    const int* __restrict__ erow, int* __restrict__ rp) {
  int r = blockIdx.x * 256 + threadIdx.x;
  if (r > M_NODES) return;
  if (r == M_NODES) { rp[r] = NUM_EDGES; return; }
  int lo = 0, hi = NUM_EDGES;
  while (lo < hi) {
    int mid = (lo + hi) >> 1;
    if (erow[mid] < r) lo = mid + 1; else hi = mid;
  }
  rp[r] = lo;
}

// ---------------- GEMM1: h1 = relu(x @ W1 + b1), bf16 out ----------------
__global__ __launch_bounds__(256) void gemm1(
    const float* __restrict__ x, const unsigned short* __restrict__ w1t,
    const float* __restrict__ b1, unsigned short* __restrict__ h1) {
  __shared__ float xs[32 * 68];
  const int wave = threadIdx.x >> 6, lane = threadIdx.x & 63;
  const int m0 = blockIdx.x * 32;
  const int n0 = wave * 64;
  const int l15 = lane & 15, quad = lane >> 4;
  const int t = threadIdx.x;

  floatx4 acc[2][4] = {};
  for (int kb = 0; kb < IN_DIM; kb += 64) {
    __syncthreads();
#pragma unroll
    for (int j = 0; j < 2; j++) {
      const int i = t * 2 + j;      // 0..511
      const int row = i >> 4;       // 0..31
      const int kq = i & 15;        // float4 index within row
      floatx4 v = *(const floatx4*)(x + (size_t)(m0 + row) * IN_DIM + kb + kq * 4);
      *(floatx4*)(xs + row * 68 + kq * 4) = v;
    }
    __syncthreads();

    bf16x8 afrag[2][2];
    bf16x8 bfrag[2][4];
#pragma unroll
    for (int ks = 0; ks < 2; ks++) {
#pragma unroll
      for (int tm = 0; tm < 2; tm++) {
        const float* p = xs + (tm * 16 + l15) * 68 + ks * 32 + quad * 8;
        floatx4 a0 = *(const floatx4*)p;
        floatx4 a1 = *(const floatx4*)(p + 4);
        bf16x8 f;
        f[0] = (__bf16)a0[0]; f[1] = (__bf16)a0[1]; f[2] = (__bf16)a0[2]; f[3] = (__bf16)a0[3];
        f[4] = (__bf16)a1[0]; f[5] = (__bf16)a1[1]; f[6] = (__bf16)a1[2]; f[7] = (__bf16)a1[3];
        afrag[ks][tm] = f;
      }
      const int k = kb + ks * 32 + quad * 8;
#pragma unroll
      for (int tn = 0; tn < 4; tn++)
        bfrag[ks][tn] = *(const bf16x8*)(w1t + (size_t)(n0 + tn * 16 + l15) * IN_DIM + k);
    }
#pragma unroll
    for (int ks = 0; ks < 2; ks++)
#pragma unroll
      for (int tm = 0; tm < 2; tm++)
#pragma unroll
        for (int tn = 0; tn < 4; tn++)
          acc[tm][tn] = __builtin_amdgcn_mfma_f32_16x16x32_bf16(afrag[ks][tm], bfrag[ks][tn], acc[tm][tn], 0, 0, 0);
  }

#pragma unroll
  for (int tm = 0; tm < 2; tm++)
#pragma unroll
    for (int tn = 0; tn < 4; tn++) {
      const int col = n0 + tn * 16 + l15;
      const float bias = b1[col];
#pragma unroll
      for (int r = 0; r < 4; r++) {
        const int row = m0 + tm * 16 + quad * 4 + r;
        float v = acc[tm][tn][r] + bias;
        v = v > 0.0f ? v : 0.0f;
        __bf16 bv = (__bf16)v;
        h1[(size_t)row * HIDDEN + col] = __builtin_bit_cast(unsigned short, bv);
      }
    }
}

// ---------------- GEMM2: T0 = h1 @ W2 + b2 -> fp32 (fA) AND bf16 (bA) ----------------
__global__ __launch_bounds__(256) void gemm2(
    const unsigned short* __restrict__ h1, const unsigned short* __restrict__ w2t,
    const float* __restrict__ b2, float* __restrict__ t0f,
    unsigned short* __restrict__ t0b) {
  const int wave = threadIdx.x >> 6, lane = threadIdx.x & 63;
  const int m0 = blockIdx.x * 128 + wave * 32;
  if (m0 >= M_NODES) return;
  const int l15 = lane & 15, quad = lane >> 4;

  floatx4 acc[2][4] = {};
  for (int kb = 0; kb < HIDDEN; kb += 32) {
    const int k = kb + quad * 8;
    bf16x8 afrag[2], bfrag[4];
#pragma unroll
    for (int tm = 0; tm < 2; tm++)
      afrag[tm] = *(const bf16x8*)(h1 + (size_t)(m0 + tm * 16 + l15) * HIDDEN + k);
#pragma unroll
    for (int tn = 0; tn < 4; tn++)
      bfrag[tn] = *(const bf16x8*)(w2t + (size_t)(tn * 16 + l15) * HIDDEN + k);
#pragma unroll
    for (int tm = 0; tm < 2; tm++)
#pragma unroll
      for (int tn = 0; tn < 4; tn++)
        acc[tm][tn] = __builtin_amdgcn_mfma_f32_16x16x32_bf16(afrag[tm], bfrag[tn], acc[tm][tn], 0, 0, 0);
  }

#pragma unroll
  for (int tm = 0; tm < 2; tm++)
#pragma unroll
    for (int tn = 0; tn < 4; tn++) {
      const int col = tn * 16 + l15;
      const float bias = b2[col];
#pragma unroll
      for (int r = 0; r < 4; r++) {
        const int row = m0 + tm * 16 + quad * 4 + r;
        const float v = acc[tm][tn][r] + bias;
        t0f[(size_t)row * NCLS + col] = v;
        __bf16 bv = (__bf16)v;
        t0b[(size_t)row * NCLS + col] = __builtin_bit_cast(unsigned short, bv);
      }
    }
}

// ---------------- batched dual-row gather ----------------
// Lane map: g = lane&7 selects edge-within-octet, q = lane>>3 selects col-octet.
// One global_load_dwordx4 per row-stream per 8 edges = 8 rows x 128B = 1KB/instr
// (8x fewer gather requests than per-edge ushort loads). Tails are masked
// iterations (clamped index, val=0) -- no scalar tail loop. Col/val loads for
// iteration b+1 are issued before iteration b's FMAs so the col->gather
// dependency pipelines to ~1 L2/L3 round trip per block of 16 edges.
__device__ __forceinline__ void cheb_gather2(
    const int* __restrict__ rp, const int* __restrict__ cols,
    const float* __restrict__ vals, const __bf16* __restrict__ tb,
    int r0, int r1, int g, int q, float (&a0)[8], float (&a1)[8]) {
  const int s0 = rp[r0], e0 = rp[r0 + 1];
  const int s1 = rp[r1], e1 = rp[r1 + 1];
  const int nb0 = (e0 - s0 + 7) >> 3;
  const int nb1 = (e1 - s1 + 7) >> 3;
  const int nb = nb0 > nb1 ? nb0 : nb1;
  const char* tbb = (const char*)tb;
  const int qoff = q << 4;

  int i0 = s0 + g, i1 = s1 + g;
  int idx0 = i0 < e0 ? i0 : (e0 - 1); idx0 = idx0 > 0 ? idx0 : 0;
  int idx1 = i1 < e1 ? i1 : (e1 - 1); idx1 = idx1 > 0 ? idx1 : 0;
  int c0 = cols[idx0], c1 = cols[idx1];
  float v0 = vals[idx0]; v0 = i0 < e0 ? v0 : 0.0f;
  float v1 = vals[idx1]; v1 = i1 < e1 ? v1 : 0.0f;

  for (int b = 0; b < nb; ++b) {
    const uintx4 d0 = *(const uintx4*)(tbb + (((size_t)(unsigned)c0) << 7) + qoff);
    const uintx4 d1 = *(const uintx4*)(tbb + (((size_t)(unsigned)c1) << 7) + qoff);
    const float cv0 = v0, cv1 = v1;
    // preload next block's cols/vals (independent of the gathers above)
    i0 += 8; i1 += 8;
    idx0 = i0 < e0 ? i0 : (e0 - 1); idx0 = idx0 > 0 ? idx0 : 0;
    idx1 = i1 < e1 ? i1 : (e1 - 1); idx1 = idx1 > 0 ? idx1 : 0;
    c0 = cols[idx0]; c1 = cols[idx1];
    v0 = vals[idx0]; v0 = i0 < e0 ? v0 : 0.0f;
    v1 = vals[idx1]; v1 = i1 < e1 ? v1 : 0.0f;
#pragma unroll
    for (int j = 0; j < 4; ++j) {
      const unsigned u0 = d0[j], u1 = d1[j];
      a0[2 * j]     += cv0 * __builtin_bit_cast(float, u0 << 16);
      a0[2 * j + 1] += cv0 * __builtin_bit_cast(float, u0 & 0xffff0000u);
      a1[2 * j]     += cv1 * __builtin_bit_cast(float, u1 << 16);
      a1[2 * j + 1] += cv1 * __builtin_bit_cast(float, u1 & 0xffff0000u);
    }
  }
  // reduce over the 8 edge-classes (lane bits 0..2); all lanes end with full sums
#pragma unroll
  for (int m = 1; m <= 4; m <<= 1) {
#pragma unroll
    for (int j = 0; j < 8; ++j) {
      a0[j] += __shfl_xor(a0[j], m, 64);
      a1[j] += __shfl_xor(a1[j], m, 64);
    }
  }
}

// ---------------- SpMM first: T1 = L T0 ; z = g0*T0 + g1*T1 ----------------
__global__ __launch_bounds__(256) void spmm_first(
    const int* __restrict__ rp, const int* __restrict__ cols,
    const float* __restrict__ vals, const __bf16* __restrict__ t0b,
    const float* __restrict__ t0f, float* __restrict__ t1f,
    unsigned short* __restrict__ t1b, const float* __restrict__ gamma,
    float* __restrict__ z) {
  const int r0 = blockIdx.x * 8 + (threadIdx.x >> 6) * 2;
  const int r1 = r0 + 1;
  const int lane = threadIdx.x & 63;
  const int g = lane & 7, q = lane >> 3;
  float a0[8] = {}, a1[8] = {};
  cheb_gather2(rp, cols, vals, t0b, r0, r1, g, q, a0, a1);

  // epilogue: lanes g==0 handle r0, lanes g==4 handle r1 (16 active lanes)
  if (g == 0 || g == 4) {
    const int rr = (g == 0) ? r0 : r1;
    float s[8];
#pragma unroll
    for (int j = 0; j < 8; ++j) s[j] = (g == 0) ? a0[j] : a1[j];
    const float g0 = gamma[0], g1 = gamma[1];
    const size_t base = (size_t)rr * NCLS + q * 8;
    const floatx4 p0 = *(const floatx4*)(t0f + base);
    const floatx4 p1 = *(const floatx4*)(t0f + base + 4);
    floatx4 slo, shi, zlo, zhi;
    ushortx8 pk;
#pragma unroll
    for (int j = 0; j < 4; ++j) {
      slo[j] = s[j];
      shi[j] = s[j + 4];
      zlo[j] = g0 * p0[j] + g1 * s[j];
      zhi[j] = g0 * p1[j] + g1 * s[j + 4];
    }
#pragma unroll
    for (int j = 0; j < 8; ++j) {
      __bf16 bv = (__bf16)s[j];
      pk[j] = __builtin_bit_cast(unsigned short, bv);
    }
    *(floatx4*)(t1f + base) = slo;
    *(floatx4*)(t1f + base + 4) = shi;
    *(ushortx8*)(t1b + base) = pk;
    *(floatx4*)(z + base) = zlo;
    *(floatx4*)(z + base + 4) = zhi;
  }
}

// ---------------- SpMM step: Tn = 2 L Tc - Tp (in place over Tp); z += g[k]*Tn ----
__global__ __launch_bounds__(256) void spmm_step(
    const int* __restrict__ rp, const int* __restrict__ cols,
    const float* __restrict__ vals, const __bf16* __restrict__ tcb,
    float* __restrict__ tpf, unsigned short* __restrict__ tnb,
    const float* __restrict__ gamma, int kidx, float* __restrict__ z) {
  const int r0 = blockIdx.x * 8 + (threadIdx.x >> 6) * 2;
  const int r1 = r0 + 1;
  const int lane = threadIdx.x & 63;
  const int g = lane & 7, q = lane >> 3;
  float a0[8] = {}, a1[8] = {};
  cheb_gather2(rp, cols, vals, tcb, r0, r1, g, q, a0, a1);

  if (g == 0 || g == 4) {
    const int rr = (g == 0) ? r0 : r1;
    float s[8];
#pragma unroll
    for (int j = 0; j < 8; ++j) s[j] = (g == 0) ? a0[j] : a1[j];
    const float gk = gamma[kidx];
    const size_t base = (size_t)rr * NCLS + q * 8;
    const floatx4 p0 = *(const floatx4*)(tpf + base);
    const floatx4 p1 = *(const floatx4*)(tpf + base + 4);
    const floatx4 z0 = *(const floatx4*)(z + base);
    const floatx4 z1 = *(const floatx4*)(z + base + 4);
    floatx4 tlo, thi, zlo, zhi;
    ushortx8 pk;
#pragma unroll
    for (int j = 0; j < 4; ++j) {
      tlo[j] = 2.0f * s[j] - p0[j];
      thi[j] = 2.0f * s[j + 4] - p1[j];
      zlo[j] = z0[j] + gk * tlo[j];
      zhi[j] = z1[j] + gk * thi[j];
    }
#pragma unroll
    for (int j = 0; j < 4; ++j) {
      __bf16 blo = (__bf16)tlo[j];
      __bf16 bhi = (__bf16)thi[j];
      pk[j] = __builtin_bit_cast(unsigned short, blo);
      pk[j + 4] = __builtin_bit_cast(unsigned short, bhi);
    }
    *(floatx4*)(tpf + base) = tlo;
    *(floatx4*)(tpf + base + 4) = thi;
    *(ushortx8*)(tnb + base) = pk;
    *(floatx4*)(z + base) = zlo;
    *(floatx4*)(z + base + 4) = zhi;
  }
}

extern "C" void kernel_launch(void* const* d_in, const int* in_sizes, int n_in,
                              void* d_out, int out_size, void* d_ws, size_t ws_size,
                              hipStream_t stream) {
  const float* x     = (const float*)d_in[0];
  const int*   erow  = (const int*)d_in[1];
  const int*   ecol  = (const int*)d_in[2];
  const float* evals = (const float*)d_in[3];
  const float* W1    = (const float*)d_in[4];
  const float* b1    = (const float*)d_in[5];
  const float* W2    = (const float*)d_in[6];
  const float* b2    = (const float*)d_in[7];
  const float* gamma = (const float*)d_in[8];

  char* ws = (char*)d_ws;
  int*            rp  = (int*)(ws + WS_ROWPTR);
  unsigned short* w1t = (unsigned short*)(ws + WS_W1T);
  unsigned short* w2t = (unsigned short*)(ws + WS_W2T);
  unsigned short* h1  = (unsigned short*)(ws + WS_H1);
  float*          fA  = (float*)(ws + WS_FA);
  float*          fB  = (float*)(ws + WS_FB);
  unsigned short* bA  = (unsigned short*)(ws + WS_BA);
  unsigned short* bB  = (unsigned short*)(ws + WS_BB);  // aliases h1 (dead after gemm2)
  float*          z   = (float*)d_out;

  prep_weights<<<576, 256, 0, stream>>>(W1, W2, w1t, w2t);
  build_rowptr<<<(M_NODES + 256) / 256, 256, 0, stream>>>(erow, rp);
  gemm1<<<M_NODES / 32, 256, 0, stream>>>(x, w1t, b1, h1);
  gemm2<<<(M_NODES + 127) / 128, 256, 0, stream>>>(h1, w2t, b2, fA, bA);

  spmm_first<<<M_NODES / 8, 256, 0, stream>>>(rp, ecol, evals, (const __bf16*)bA,
                                              fA, fB, bB, gamma, z);

  float*          fprev = fA;
  float*          fothr = fB;
  unsigned short* bcur  = bB;
  unsigned short* bnext = bA;
  for (int k = 2; k <= 8; ++k) {
    spmm_step<<<M_NODES / 8, 256, 0, stream>>>(rp, ecol, evals, (const __bf16*)bcur,
                                               fprev, bnext, gamma, k, z);
    float* tf = fprev; fprev = fothr; fothr = tf;
    unsigned short* tb = bcur; bcur = bnext; bnext = tb;
  }
}